// Round 1
// baseline (102.101 us; speedup 1.0000x reference)
//
#include <hip/hip_runtime.h>

// SlotAttention: B=8, L=256, D=256, K=64
// out[b,i,:] = concat(inputs[b,i,:], context[b,i,:])
// scores[b,i,j] = sum_k W2[k]*tanh(qi[b,i,k]+kj[b,j,k]); attn = softmax_j; ctx = attn @ inputs[b]

#define Bn 8
#define Ln 256
#define Dn 256
#define Kn 64
#define ROWS (Bn*Ln)       // 2048
#define IPB 4              // query rows per block in attn kernel

__device__ __forceinline__ float fast_tanh(float x) {
    // tanh(x) = 1 - 2/(exp(2x)+1); saturates correctly at +/-inf
    float e = __expf(2.0f * x);
    return 1.0f - 2.0f / (e + 1.0f);
}

// ---------------- Kernel A: projection ----------------
// QK[row][c], row in [0,2048), c in [0,128):
//   c <  64: qi = sum_d X[row,d]*W1[c, d]
//   c >= 64: kj = sum_d X[row,d]*W1[c-64, 256+d]
__global__ __launch_bounds__(128) void proj_kernel(
    const float* __restrict__ X,    // (2048,256)
    const float* __restrict__ W1,   // (64,512)
    float* __restrict__ QK)         // (2048,128)
{
    __shared__ float Xs[8 * 256];
    const int tid = threadIdx.x;
    const int r0 = blockIdx.x * 8;

    // stage 8 rows of X (2048 floats = 512 float4), coalesced
    const float4* Xg4 = (const float4*)(X + r0 * Dn);
    float4* Xs4 = (float4*)Xs;
    #pragma unroll
    for (int idx = tid; idx < 512; idx += 128) Xs4[idx] = Xg4[idx];
    __syncthreads();

    const int k = tid & 63, half = tid >> 6;
    const float4* Wrow = (const float4*)(W1 + k * (2 * Dn) + half * Dn);
    float acc[8] = {0, 0, 0, 0, 0, 0, 0, 0};
    #pragma unroll 8
    for (int d4 = 0; d4 < 64; ++d4) {
        float4 w = Wrow[d4];
        #pragma unroll
        for (int r = 0; r < 8; ++r) {
            float4 x = ((const float4*)(Xs + r * Dn))[d4];  // LDS broadcast
            float a = acc[r];
            a = fmaf(w.x, x.x, a);
            a = fmaf(w.y, x.y, a);
            a = fmaf(w.z, x.z, a);
            a = fmaf(w.w, x.w, a);
            acc[r] = a;
        }
    }
    #pragma unroll
    for (int r = 0; r < 8; ++r)
        QK[(r0 + r) * 128 + tid] = acc[r];
}

// ---------------- Kernel B: scores + softmax + context ----------------
// grid = (B*L/IPB) blocks, 256 threads. Block handles rows i0..i0+3 of batch b.
__global__ __launch_bounds__(256) void attn_kernel(
    const float* __restrict__ X,    // (2048,256)
    const float* __restrict__ QK,   // (2048,128)
    const float* __restrict__ W2,   // (64,)
    float* __restrict__ out)        // (2048,512)
{
    __shared__ float qi_s[IPB * Kn];   // 1 KB
    __shared__ float w2_s[Kn];
    __shared__ float S[IPB * Ln];      // 4 KB: scores then attn

    const int tid = threadIdx.x;
    const int b  = blockIdx.x / (Ln / IPB);
    const int i0 = (blockIdx.x % (Ln / IPB)) * IPB;

    if (tid < Kn) w2_s[tid] = W2[tid];
    {   // qi for the 4 query rows: 256 floats, one per thread
        int ii = tid >> 6, kk = tid & 63;
        qi_s[ii * Kn + kk] = QK[(b * Ln + i0 + ii) * 128 + kk];
    }

    // each thread owns key row j = tid: prefetch kj row (64 floats) to registers
    float kjrow[Kn];
    const float4* kj4 = (const float4*)(QK + (b * Ln + tid) * 128 + 64);
    #pragma unroll
    for (int q = 0; q < 16; ++q) {
        float4 v = kj4[q];
        kjrow[q * 4 + 0] = v.x; kjrow[q * 4 + 1] = v.y;
        kjrow[q * 4 + 2] = v.z; kjrow[q * 4 + 3] = v.w;
    }
    __syncthreads();

    // Phase 1: scores for 4 i's at this j
    float s[IPB] = {0, 0, 0, 0};
    #pragma unroll
    for (int kk = 0; kk < Kn; ++kk) {     // full unroll: kjrow stays in regs
        float w  = w2_s[kk];
        float kv = kjrow[kk];
        #pragma unroll
        for (int i = 0; i < IPB; ++i)
            s[i] = fmaf(w, fast_tanh(qi_s[i * Kn + kk] + kv), s[i]);
    }
    #pragma unroll
    for (int i = 0; i < IPB; ++i) S[i * Ln + tid] = s[i];
    __syncthreads();

    // Phase 2: softmax over j; wave w handles query row i=w (4 waves, 4 rows)
    {
        const int wv = tid >> 6, lane = tid & 63;
        float v0 = S[wv * Ln + lane];
        float v1 = S[wv * Ln + 64 + lane];
        float v2 = S[wv * Ln + 128 + lane];
        float v3 = S[wv * Ln + 192 + lane];
        float m = fmaxf(fmaxf(v0, v1), fmaxf(v2, v3));
        #pragma unroll
        for (int off = 32; off > 0; off >>= 1)
            m = fmaxf(m, __shfl_xor(m, off));
        float e0 = __expf(v0 - m), e1 = __expf(v1 - m);
        float e2 = __expf(v2 - m), e3 = __expf(v3 - m);
        float sum = e0 + e1 + e2 + e3;
        #pragma unroll
        for (int off = 32; off > 0; off >>= 1)
            sum += __shfl_xor(sum, off);
        float inv = 1.0f / sum;
        S[wv * Ln + lane]       = e0 * inv;
        S[wv * Ln + 64 + lane]  = e1 * inv;
        S[wv * Ln + 128 + lane] = e2 * inv;
        S[wv * Ln + 192 + lane] = e3 * inv;
    }
    __syncthreads();

    // Phase 3: context. thread d = tid accumulates over j; coalesced X reads.
    float acc[IPB] = {0, 0, 0, 0};
    const float* Xb = X + b * Ln * Dn;
    for (int j = 0; j < Ln; ++j) {
        float x = Xb[j * Dn + tid];
        #pragma unroll
        for (int i = 0; i < IPB; ++i)
            acc[i] = fmaf(S[i * Ln + j], x, acc[i]);  // LDS broadcast
    }
    #pragma unroll
    for (int i = 0; i < IPB; ++i) {
        int row = b * Ln + i0 + i;
        out[row * (2 * Dn) + tid]      = X[row * Dn + tid];
        out[row * (2 * Dn) + Dn + tid] = acc[i];
    }
}

extern "C" void kernel_launch(void* const* d_in, const int* in_sizes, int n_in,
                              void* d_out, int out_size, void* d_ws, size_t ws_size,
                              hipStream_t stream) {
    const float* X  = (const float*)d_in[0];   // (8,256,256)
    const float* W1 = (const float*)d_in[1];   // (64,512)
    const float* W2 = (const float*)d_in[2];   // (1,64)
    float* out = (float*)d_out;                // (8,256,512)
    float* QK  = (float*)d_ws;                 // (2048,128) = 1 MB scratch

    proj_kernel<<<ROWS / 8, 128, 0, stream>>>(X, W1, QK);
    attn_kernel<<<ROWS / IPB, 256, 0, stream>>>(X, QK, W2, out);
}

// Round 2
// 95.797 us; speedup vs baseline: 1.0658x; 1.0658x over previous
//
#include <hip/hip_runtime.h>

// SlotAttention: B=8, L=256, D=256, K=64
// out[b,i,:] = concat(inputs[b,i,:], context[b,i,:])
// scores[b,i,j] = sum_k W2[k]*tanh(qi[b,i,k]+kj[b,j,k]); attn = softmax_j; ctx = attn @ inputs[b]
//
// Round-2 structure:
//   proj stores TANH of the projections (tq, tk). Then
//   tanh(q+k) = (tq+tk)/(1+tq*tk)  -- moves 33.5M tanh out of the hot loop,
//   replaced by one fast rcp. tq/tk clamped to avoid 0/0 at saturation.

#define Bn 8
#define Ln 256
#define Dn 256
#define Kn 64
#define ROWS (Bn*Ln)       // 2048
#define IPB 4              // query rows per block in attn kernel

// ---------------- Kernel A: projection + tanh ----------------
// QK[row][c], row in [0,2048), c in [0,128):
//   c <  64: tq = tanh(sum_d X[row,d]*W1[c, d])
//   c >= 64: tk = tanh(sum_d X[row,d]*W1[c-64, 256+d])
__global__ __launch_bounds__(128) void proj_kernel(
    const float* __restrict__ X,    // (2048,256)
    const float* __restrict__ W1,   // (64,512)
    float* __restrict__ QK)         // (2048,128)
{
    __shared__ float Xs[8 * 256];
    const int tid = threadIdx.x;
    const int r0 = blockIdx.x * 8;

    const float4* Xg4 = (const float4*)(X + r0 * Dn);
    float4* Xs4 = (float4*)Xs;
    #pragma unroll
    for (int idx = tid; idx < 512; idx += 128) Xs4[idx] = Xg4[idx];
    __syncthreads();

    const int k = tid & 63, half = tid >> 6;
    const float4* Wrow = (const float4*)(W1 + k * (2 * Dn) + half * Dn);
    float acc[8] = {0, 0, 0, 0, 0, 0, 0, 0};
    #pragma unroll 8
    for (int d4 = 0; d4 < 64; ++d4) {
        float4 w = Wrow[d4];
        #pragma unroll
        for (int r = 0; r < 8; ++r) {
            float4 x = ((const float4*)(Xs + r * Dn))[d4];  // LDS broadcast
            float a = acc[r];
            a = fmaf(w.x, x.x, a);
            a = fmaf(w.y, x.y, a);
            a = fmaf(w.z, x.z, a);
            a = fmaf(w.w, x.w, a);
            acc[r] = a;
        }
    }
    #pragma unroll
    for (int r = 0; r < 8; ++r) {
        // precise-enough tanh (cold path: 262K calls total)
        float e = __expf(2.0f * acc[r]);
        float t = 1.0f - 2.0f / (e + 1.0f);
        // clamp so 1 + tq*tk can never hit exactly 0 in the identity
        t = fminf(0.99999988f, fmaxf(-0.99999988f, t));
        QK[(r0 + r) * 128 + tid] = t;
    }
}

// ---------------- Kernel B: scores + softmax + context ----------------
// grid = (B*L/IPB) blocks, 256 threads. Block handles rows i0..i0+3 of batch b.
__global__ __launch_bounds__(256) void attn_kernel(
    const float* __restrict__ X,    // (2048,256)
    const float* __restrict__ QK,   // (2048,128) tanh'd
    const float* __restrict__ W2,   // (64,)
    float* __restrict__ out)        // (2048,512)
{
    __shared__ float tq_s[IPB * Kn];   // [i][k], 1 KB
    __shared__ float w2_s[Kn];
    __shared__ float S[Ln * IPB];      // [j][i]  (transposed vs round 1!)

    const int tid = threadIdx.x;
    const int b  = blockIdx.x / (Ln / IPB);
    const int i0 = (blockIdx.x % (Ln / IPB)) * IPB;

    if (tid < Kn) w2_s[tid] = W2[tid];
    {   // tq for the 4 query rows: 256 floats, one per thread
        int ii = tid >> 6, kk = tid & 63;
        tq_s[ii * Kn + kk] = QK[(b * Ln + i0 + ii) * 128 + kk];
    }

    // each thread owns key row j = tid: prefetch tk row (64 floats) to registers
    float tkr[Kn];
    const float4* kj4 = (const float4*)(QK + (b * Ln + tid) * 128 + 64);
    #pragma unroll
    for (int q = 0; q < 16; ++q) {
        float4 v = kj4[q];
        tkr[q * 4 + 0] = v.x; tkr[q * 4 + 1] = v.y;
        tkr[q * 4 + 2] = v.z; tkr[q * 4 + 3] = v.w;
    }
    __syncthreads();

    // Phase 1: scores for 4 i's at this j, via tanh addition identity.
    float s[IPB] = {0, 0, 0, 0};
    const float4* w4  = (const float4*)w2_s;
    const float4* q4a = (const float4*)(tq_s);
    const float4* q4b = (const float4*)(tq_s + Kn);
    const float4* q4c = (const float4*)(tq_s + 2 * Kn);
    const float4* q4d = (const float4*)(tq_s + 3 * Kn);
    #pragma unroll
    for (int k4 = 0; k4 < 16; ++k4) {      // b128 broadcast LDS reads
        float4 w  = w4[k4];
        float4 q0 = q4a[k4], q1 = q4b[k4], q2 = q4c[k4], q3 = q4d[k4];
        #pragma unroll
        for (int c = 0; c < 4; ++c) {
            float tk = tkr[k4 * 4 + c];
            float wk = (c == 0) ? w.x : (c == 1) ? w.y : (c == 2) ? w.z : w.w;
            float tq0 = (c == 0) ? q0.x : (c == 1) ? q0.y : (c == 2) ? q0.z : q0.w;
            float tq1 = (c == 0) ? q1.x : (c == 1) ? q1.y : (c == 2) ? q1.z : q1.w;
            float tq2 = (c == 0) ? q2.x : (c == 1) ? q2.y : (c == 2) ? q2.z : q2.w;
            float tq3 = (c == 0) ? q3.x : (c == 1) ? q3.y : (c == 2) ? q3.z : q3.w;
            // tanh(q+k) = (tq+tk)/(1+tq*tk)
            float n0 = tq0 + tk, d0 = fmaf(tq0, tk, 1.0f);
            float n1 = tq1 + tk, d1 = fmaf(tq1, tk, 1.0f);
            float n2 = tq2 + tk, d2 = fmaf(tq2, tk, 1.0f);
            float n3 = tq3 + tk, d3 = fmaf(tq3, tk, 1.0f);
            s[0] = fmaf(wk, n0 * __builtin_amdgcn_rcpf(d0), s[0]);
            s[1] = fmaf(wk, n1 * __builtin_amdgcn_rcpf(d1), s[1]);
            s[2] = fmaf(wk, n2 * __builtin_amdgcn_rcpf(d2), s[2]);
            s[3] = fmaf(wk, n3 * __builtin_amdgcn_rcpf(d3), s[3]);
        }
    }
    ((float4*)S)[tid] = make_float4(s[0], s[1], s[2], s[3]);   // S[j][i]
    __syncthreads();

    // Phase 2: softmax over j; wave wv handles query row i=wv
    {
        const int wv = tid >> 6, lane = tid & 63;
        float v0 = S[(lane      ) * IPB + wv];
        float v1 = S[(lane +  64) * IPB + wv];
        float v2 = S[(lane + 128) * IPB + wv];
        float v3 = S[(lane + 192) * IPB + wv];
        float m = fmaxf(fmaxf(v0, v1), fmaxf(v2, v3));
        #pragma unroll
        for (int off = 32; off > 0; off >>= 1)
            m = fmaxf(m, __shfl_xor(m, off));
        float e0 = __expf(v0 - m), e1 = __expf(v1 - m);
        float e2 = __expf(v2 - m), e3 = __expf(v3 - m);
        float sum = e0 + e1 + e2 + e3;
        #pragma unroll
        for (int off = 32; off > 0; off >>= 1)
            sum += __shfl_xor(sum, off);
        float inv = 1.0f / sum;
        S[(lane      ) * IPB + wv] = e0 * inv;
        S[(lane +  64) * IPB + wv] = e1 * inv;
        S[(lane + 128) * IPB + wv] = e2 * inv;
        S[(lane + 192) * IPB + wv] = e3 * inv;
    }
    __syncthreads();

    // Phase 3: context. thread d = tid accumulates over j.
    // One broadcast ds_read_b128 per j (attn for all 4 i's), one coalesced
    // global load per j; unroll x4 so loads pipeline.
    float a0 = 0, a1 = 0, a2 = 0, a3 = 0;
    const float* Xb = X + b * Ln * Dn;
    const float4* S4 = (const float4*)S;
    #pragma unroll 4
    for (int j = 0; j < Ln; ++j) {
        float4 at = S4[j];               // LDS broadcast, 16B
        float x = Xb[j * Dn + tid];
        a0 = fmaf(at.x, x, a0);
        a1 = fmaf(at.y, x, a1);
        a2 = fmaf(at.z, x, a2);
        a3 = fmaf(at.w, x, a3);
    }
    {
        int row = b * Ln + i0;
        out[(row + 0) * (2 * Dn) + tid]      = X[(row + 0) * Dn + tid];
        out[(row + 1) * (2 * Dn) + tid]      = X[(row + 1) * Dn + tid];
        out[(row + 2) * (2 * Dn) + tid]      = X[(row + 2) * Dn + tid];
        out[(row + 3) * (2 * Dn) + tid]      = X[(row + 3) * Dn + tid];
        out[(row + 0) * (2 * Dn) + Dn + tid] = a0;
        out[(row + 1) * (2 * Dn) + Dn + tid] = a1;
        out[(row + 2) * (2 * Dn) + Dn + tid] = a2;
        out[(row + 3) * (2 * Dn) + Dn + tid] = a3;
    }
}

extern "C" void kernel_launch(void* const* d_in, const int* in_sizes, int n_in,
                              void* d_out, int out_size, void* d_ws, size_t ws_size,
                              hipStream_t stream) {
    const float* X  = (const float*)d_in[0];   // (8,256,256)
    const float* W1 = (const float*)d_in[1];   // (64,512)
    const float* W2 = (const float*)d_in[2];   // (1,64)
    float* out = (float*)d_out;                // (8,256,512)
    float* QK  = (float*)d_ws;                 // (2048,128) = 1 MB scratch

    proj_kernel<<<ROWS / 8, 128, 0, stream>>>(X, W1, QK);
    attn_kernel<<<ROWS / IPB, 256, 0, stream>>>(X, QK, W2, out);
}

// Round 3
// 83.212 us; speedup vs baseline: 1.2270x; 1.1512x over previous
//
#include <hip/hip_runtime.h>

// SlotAttention: B=8, L=256, D=256, K=64
// out[b,i,:] = concat(inputs[b,i,:], context[b,i,:])
// scores[b,i,j] = sum_k W2[k]*tanh(qi[b,i,k]+kj[b,j,k]); attn = softmax_j; ctx = attn @ inputs[b]
//
// Round-3:
//  - proj: 512 blocks x 4 rows (was 256 x 8) -> 4 waves/CU for latency hiding
//  - attn phase 3: j-range split across the 4 waves, float4 X loads,
//    cross-wave LDS reduction; all output stores b128.
//  - tanh identity (round 2) kept: tanh(q+k) = (tq+tk)/(1+tq*tk)

#define Bn 8
#define Ln 256
#define Dn 256
#define Kn 64
#define ROWS (Bn*Ln)       // 2048
#define IPB 4              // query rows per block in attn kernel

// ---------------- Kernel A: projection + tanh ----------------
// QK[row][c]: c<64 -> tanh(qi[k=c]), c>=64 -> tanh(kj[k=c-64])
__global__ __launch_bounds__(128) void proj_kernel(
    const float* __restrict__ X,    // (2048,256)
    const float* __restrict__ W1,   // (64,512)
    float* __restrict__ QK)         // (2048,128)
{
    __shared__ float Xs[4 * 256];
    const int tid = threadIdx.x;
    const int r0 = blockIdx.x * 4;

    // stage 4 rows (256 float4), coalesced
    const float4* Xg4 = (const float4*)(X + r0 * Dn);
    float4* Xs4 = (float4*)Xs;
    #pragma unroll
    for (int idx = tid; idx < 256; idx += 128) Xs4[idx] = Xg4[idx];
    __syncthreads();

    const int k = tid & 63, half = tid >> 6;
    const float4* Wrow = (const float4*)(W1 + k * (2 * Dn) + half * Dn);
    float acc[4] = {0, 0, 0, 0};
    #pragma unroll 8
    for (int d4 = 0; d4 < 64; ++d4) {
        float4 w = Wrow[d4];
        #pragma unroll
        for (int r = 0; r < 4; ++r) {
            float4 x = ((const float4*)(Xs + r * Dn))[d4];  // uniform LDS broadcast
            float a = acc[r];
            a = fmaf(w.x, x.x, a);
            a = fmaf(w.y, x.y, a);
            a = fmaf(w.z, x.z, a);
            a = fmaf(w.w, x.w, a);
            acc[r] = a;
        }
    }
    #pragma unroll
    for (int r = 0; r < 4; ++r) {
        float e = __expf(2.0f * acc[r]);
        float t = 1.0f - 2.0f / (e + 1.0f);
        t = fminf(0.99999988f, fmaxf(-0.99999988f, t));  // keep 1+tq*tk > 0
        QK[(r0 + r) * 128 + tid] = t;
    }
}

// ---------------- Kernel B: scores + softmax + context ----------------
// grid = (B*L/IPB) blocks, 256 threads. Block handles rows i0..i0+3 of batch b.
__global__ __launch_bounds__(256) void attn_kernel(
    const float* __restrict__ X,    // (2048,256)
    const float* __restrict__ QK,   // (2048,128) tanh'd
    const float* __restrict__ W2,   // (64,)
    float* __restrict__ out)        // (2048,512)
{
    __shared__ float tq_s[IPB * Kn];        // [i][k], 1 KB
    __shared__ float w2_s[Kn];
    __shared__ float S[Ln * IPB];           // [j][i], 4 KB
    __shared__ float4 red[4 * IPB * 64];    // [wv][i][dquad], 16 KB

    const int tid = threadIdx.x;
    const int b  = blockIdx.x / (Ln / IPB);
    const int i0 = (blockIdx.x % (Ln / IPB)) * IPB;

    if (tid < Kn) w2_s[tid] = W2[tid];
    {   // tq for the 4 query rows
        int ii = tid >> 6, kk = tid & 63;
        tq_s[ii * Kn + kk] = QK[(b * Ln + i0 + ii) * 128 + kk];
    }

    // thread owns key row j = tid: prefetch tk row (64 floats) to registers
    float tkr[Kn];
    const float4* kj4 = (const float4*)(QK + (b * Ln + tid) * 128 + 64);
    #pragma unroll
    for (int q = 0; q < 16; ++q) {
        float4 v = kj4[q];
        tkr[q * 4 + 0] = v.x; tkr[q * 4 + 1] = v.y;
        tkr[q * 4 + 2] = v.z; tkr[q * 4 + 3] = v.w;
    }
    __syncthreads();

    // Phase 1: scores for 4 i's at this j, via tanh addition identity.
    float s[IPB] = {0, 0, 0, 0};
    const float4* w4  = (const float4*)w2_s;
    const float4* q4a = (const float4*)(tq_s);
    const float4* q4b = (const float4*)(tq_s + Kn);
    const float4* q4c = (const float4*)(tq_s + 2 * Kn);
    const float4* q4d = (const float4*)(tq_s + 3 * Kn);
    #pragma unroll
    for (int k4 = 0; k4 < 16; ++k4) {
        float4 w  = w4[k4];
        float4 q0 = q4a[k4], q1 = q4b[k4], q2 = q4c[k4], q3 = q4d[k4];
        #pragma unroll
        for (int c = 0; c < 4; ++c) {
            float tk = tkr[k4 * 4 + c];
            float wk = (c == 0) ? w.x : (c == 1) ? w.y : (c == 2) ? w.z : w.w;
            float tq0 = (c == 0) ? q0.x : (c == 1) ? q0.y : (c == 2) ? q0.z : q0.w;
            float tq1 = (c == 0) ? q1.x : (c == 1) ? q1.y : (c == 2) ? q1.z : q1.w;
            float tq2 = (c == 0) ? q2.x : (c == 1) ? q2.y : (c == 2) ? q2.z : q2.w;
            float tq3 = (c == 0) ? q3.x : (c == 1) ? q3.y : (c == 2) ? q3.z : q3.w;
            float n0 = tq0 + tk, d0 = fmaf(tq0, tk, 1.0f);
            float n1 = tq1 + tk, d1 = fmaf(tq1, tk, 1.0f);
            float n2 = tq2 + tk, d2 = fmaf(tq2, tk, 1.0f);
            float n3 = tq3 + tk, d3 = fmaf(tq3, tk, 1.0f);
            s[0] = fmaf(wk, n0 * __builtin_amdgcn_rcpf(d0), s[0]);
            s[1] = fmaf(wk, n1 * __builtin_amdgcn_rcpf(d1), s[1]);
            s[2] = fmaf(wk, n2 * __builtin_amdgcn_rcpf(d2), s[2]);
            s[3] = fmaf(wk, n3 * __builtin_amdgcn_rcpf(d3), s[3]);
        }
    }
    ((float4*)S)[tid] = make_float4(s[0], s[1], s[2], s[3]);   // S[j][i]
    __syncthreads();

    // Phase 2: softmax over j; wave wv handles query row i=wv
    {
        const int wv = tid >> 6, lane = tid & 63;
        float v0 = S[(lane      ) * IPB + wv];
        float v1 = S[(lane +  64) * IPB + wv];
        float v2 = S[(lane + 128) * IPB + wv];
        float v3 = S[(lane + 192) * IPB + wv];
        float m = fmaxf(fmaxf(v0, v1), fmaxf(v2, v3));
        #pragma unroll
        for (int off = 32; off > 0; off >>= 1)
            m = fmaxf(m, __shfl_xor(m, off));
        float e0 = __expf(v0 - m), e1 = __expf(v1 - m);
        float e2 = __expf(v2 - m), e3 = __expf(v3 - m);
        float sum = e0 + e1 + e2 + e3;
        #pragma unroll
        for (int off = 32; off > 0; off >>= 1)
            sum += __shfl_xor(sum, off);
        float inv = 1.0f / sum;
        S[(lane      ) * IPB + wv] = e0 * inv;
        S[(lane +  64) * IPB + wv] = e1 * inv;
        S[(lane + 128) * IPB + wv] = e2 * inv;
        S[(lane + 192) * IPB + wv] = e3 * inv;
    }
    __syncthreads();

    // Phase 3: context, j split across waves. Wave wv covers j in [wv*64, wv*64+64);
    // lane l covers columns d = 4l..4l+3 (float4). One uniform b128 attn read +
    // one coalesced float4 X read per j.
    {
        const int wv = tid >> 6, lane = tid & 63;
        float4 acc0 = {0,0,0,0}, acc1 = {0,0,0,0}, acc2 = {0,0,0,0}, acc3 = {0,0,0,0};
        const float4* Xb4 = (const float4*)(X + b * Ln * Dn);
        const float4* S4  = (const float4*)S;
        const int jbase = wv * 64;
        #pragma unroll 8
        for (int jj = 0; jj < 64; ++jj) {
            int j = jbase + jj;
            float4 at = S4[j];                 // attn[i=0..3][j], uniform broadcast
            float4 x  = Xb4[j * 64 + lane];    // X[b,j,4l..4l+3], coalesced 1 KB/wave
            acc0.x = fmaf(at.x, x.x, acc0.x); acc0.y = fmaf(at.x, x.y, acc0.y);
            acc0.z = fmaf(at.x, x.z, acc0.z); acc0.w = fmaf(at.x, x.w, acc0.w);
            acc1.x = fmaf(at.y, x.x, acc1.x); acc1.y = fmaf(at.y, x.y, acc1.y);
            acc1.z = fmaf(at.y, x.z, acc1.z); acc1.w = fmaf(at.y, x.w, acc1.w);
            acc2.x = fmaf(at.z, x.x, acc2.x); acc2.y = fmaf(at.z, x.y, acc2.y);
            acc2.z = fmaf(at.z, x.z, acc2.z); acc2.w = fmaf(at.z, x.w, acc2.w);
            acc3.x = fmaf(at.w, x.x, acc3.x); acc3.y = fmaf(at.w, x.y, acc3.y);
            acc3.z = fmaf(at.w, x.z, acc3.z); acc3.w = fmaf(at.w, x.w, acc3.w);
        }
        red[(wv * IPB + 0) * 64 + lane] = acc0;
        red[(wv * IPB + 1) * 64 + lane] = acc1;
        red[(wv * IPB + 2) * 64 + lane] = acc2;
        red[(wv * IPB + 3) * 64 + lane] = acc3;
    }
    __syncthreads();

    // Cross-wave reduce + store. Thread tid: i = tid>>6, dquad q = tid&63.
    {
        const int i = tid >> 6, q = tid & 63;
        float4 p0 = red[(0 * IPB + i) * 64 + q];
        float4 p1 = red[(1 * IPB + i) * 64 + q];
        float4 p2 = red[(2 * IPB + i) * 64 + q];
        float4 p3 = red[(3 * IPB + i) * 64 + q];
        float4 c;
        c.x = (p0.x + p1.x) + (p2.x + p3.x);
        c.y = (p0.y + p1.y) + (p2.y + p3.y);
        c.z = (p0.z + p1.z) + (p2.z + p3.z);
        c.w = (p0.w + p1.w) + (p2.w + p3.w);
        const int row = b * Ln + i0 + i;
        float4 xcopy = ((const float4*)(X + row * Dn))[q];
        ((float4*)(out + row * 2 * Dn))[q]      = xcopy;  // inputs half
        ((float4*)(out + row * 2 * Dn + Dn))[q] = c;      // context half
    }
}

extern "C" void kernel_launch(void* const* d_in, const int* in_sizes, int n_in,
                              void* d_out, int out_size, void* d_ws, size_t ws_size,
                              hipStream_t stream) {
    const float* X  = (const float*)d_in[0];   // (8,256,256)
    const float* W1 = (const float*)d_in[1];   // (64,512)
    const float* W2 = (const float*)d_in[2];   // (1,64)
    float* out = (float*)d_out;                // (8,256,512)
    float* QK  = (float*)d_ws;                 // (2048,128) = 1 MB scratch

    proj_kernel<<<ROWS / 4, 128, 0, stream>>>(X, W1, QK);
    attn_kernel<<<ROWS / IPB, 256, 0, stream>>>(X, QK, W2, out);
}